// Round 12
// baseline (1007.569 us; speedup 1.0000x reference)
//
#include <hip/hip_runtime.h>

// GPT forward, MI355X gfx950.
// Shapes: V=371 E=512 H=8 L=8 B=4 T=1024 D=64, N=B*T=4096.
// Inputs float32 (runtime-detected, bf16 supported); output matches input fmt.
// r21: r20 + proj moved to gemm_sk z=2 (1024 blocks = 4/CU vs 2/CU on
// gemm_nt). Clean retry of r18's confounded proj-sk: r18's regression is
// attributed to fcp z=4 (41us dispatches, FETCH 66MB), and r18's gemm_sk
// lacked the XCD swizzle r19 validated (-46us). proj has res==out==xw so the
// atomicAdd epilogue needs no init/reduce. Everything else = r20 (T1 swizzle
// on all panel-sharing kernels, attn v6 in-reg P + setprio, fcp sk z=2).

#define VOCAB 371
#define VPAD  384
#define EMB   512
#define NH    8
#define NL    8
#define TS    1024
#define NTOK  4096
#define NEG_INF (-1e30f)

typedef unsigned short ushort_t;
typedef __attribute__((ext_vector_type(8))) short short8;
typedef __attribute__((ext_vector_type(4))) float f32x4;

__device__ inline float bf2f(ushort_t b) {
    unsigned int u = ((unsigned int)b) << 16;
    float f; __builtin_memcpy(&f, &u, 4); return f;
}
__device__ inline ushort_t f2bf(float f) {
    unsigned int u; __builtin_memcpy(&u, &f, 4);
    u = (u + 0x7fff + ((u >> 16) & 1)) >> 16;   // RNE
    return (ushort_t)u;
}

// T1 XCD swizzle: co-locate all x-blocks of a y-group on one XCD.
// Requires gridDim.y % 8 == 0. Returns (xl, yl).
__device__ inline void xcd_swz(int& xl, int& yl) {
    const int slot = (int)blockIdx.y * (int)gridDim.x + (int)blockIdx.x;
    const int xcd = slot & 7, idx = slot >> 3;
    const int ypg = (int)gridDim.y >> 3;
    yl = xcd + 8 * (idx % ypg);
    xl = idx / ypg;
}

// ---------------- dtype probe ---------------------------------------------------
__global__ __launch_bounds__(64) void detect_k(const ushort_t* __restrict__ w,
        int* __restrict__ flag)
{
    int i = threadIdx.x;
    float v = bf2f(w[2 * i]);
    bool ok = (__builtin_fabsf(v) <= 4.0f);
    unsigned long long m = __ballot(ok);
    if (i == 0) flag[0] = (__popcll(m) >= 56) ? 1 : 0;   // 1 = bf16, 0 = float32
}

// ---------------- ws-too-small sentinel ----------------------------------------
__global__ __launch_bounds__(256) void sentinel_k(ushort_t* __restrict__ out, int n)
{
    int i = blockIdx.x * 256 + threadIdx.x;
    if (i < n) out[i] = 0x447A;
}

// ---------------- embedding ----------------------------------------------------
__global__ __launch_bounds__(256) void embed_k(const int* __restrict__ idx,
        const void* __restrict__ wte, const void* __restrict__ wpe,
        float* __restrict__ x, const int* __restrict__ flag)
{
    int n = blockIdx.x, tid = threadIdx.x;
    int t = n & (TS - 1);
    int v = idx[n];
    size_t o = (size_t)n * EMB;
    float a0, a1, b0, b1;
    if (*flag) {
        const ushort_t* te = (const ushort_t*)wte; const ushort_t* pe = (const ushort_t*)wpe;
        a0 = bf2f(te[v * EMB + tid]); a1 = bf2f(te[v * EMB + 256 + tid]);
        b0 = bf2f(pe[t * EMB + tid]); b1 = bf2f(pe[t * EMB + 256 + tid]);
    } else {
        const float* te = (const float*)wte; const float* pe = (const float*)wpe;
        a0 = te[v * EMB + tid]; a1 = te[v * EMB + 256 + tid];
        b0 = pe[t * EMB + tid]; b1 = pe[t * EMB + 256 + tid];
    }
    x[o + tid] = a0 + b0;
    x[o + 256 + tid] = a1 + b1;
}

// ---------------- layernorm v2: one wave per row, no barriers ------------------
__global__ __launch_bounds__(256) void ln_k(const float* __restrict__ x,
        const void* __restrict__ w, long woff, ushort_t* __restrict__ out,
        const int* __restrict__ flag)
{
    const int row = blockIdx.x * 4 + (threadIdx.x >> 6);
    const int lane = threadIdx.x & 63;
    const float* xr = x + (size_t)row * EMB + lane * 8;
    float4 f0 = *(const float4*)xr;
    float4 f1 = *(const float4*)(xr + 4);
    float v[8] = {f0.x, f0.y, f0.z, f0.w, f1.x, f1.y, f1.z, f1.w};
    float s = ((v[0] + v[1]) + (v[2] + v[3])) + ((v[4] + v[5]) + (v[6] + v[7]));
#pragma unroll
    for (int off = 32; off > 0; off >>= 1) s += __shfl_xor(s, off, 64);
    float mean = s * (1.0f / EMB);
    float s2 = 0.f;
#pragma unroll
    for (int j = 0; j < 8; ++j) { v[j] -= mean; s2 += v[j] * v[j]; }
#pragma unroll
    for (int off = 32; off > 0; off >>= 1) s2 += __shfl_xor(s2, off, 64);
    float rs = rsqrtf(s2 * (1.0f / EMB) + 1e-5f);
    float g[8];
    if (*flag) {
        const ushort_t* wb = (const ushort_t*)w + woff + lane * 8;
        ushort_t tmp[8];
        *(uint4*)tmp = *(const uint4*)wb;
#pragma unroll
        for (int j = 0; j < 8; ++j) g[j] = bf2f(tmp[j]);
    } else {
        const float* wf = (const float*)w + woff + lane * 8;
        float4 g0 = *(const float4*)wf;
        float4 g1 = *(const float4*)(wf + 4);
        g[0] = g0.x; g[1] = g0.y; g[2] = g0.z; g[3] = g0.w;
        g[4] = g1.x; g[5] = g1.y; g[6] = g1.z; g[7] = g1.w;
    }
    ushort_t ob[8];
#pragma unroll
    for (int j = 0; j < 8; ++j) ob[j] = f2bf(v[j] * rs * g[j]);
    *(uint4*)(out + (size_t)row * EMB + lane * 8) = *(uint4*)ob;
}

// ---------------- weight transpose v3: [K,N] dtype -> bf16 [N,K] ---------------
__global__ __launch_bounds__(256) void wtrans_k(const void* __restrict__ aw,
        const void* __restrict__ pw, const void* __restrict__ fw,
        const void* __restrict__ fpw, long l, ushort_t* __restrict__ wbuf,
        const int* __restrict__ flag)
{
    __shared__ float tile[64][65];
    const int isbf = *flag;
    long lay = (l < 0) ? (long)blockIdx.z : l;
    ushort_t* obase = wbuf + ((l < 0) ? (size_t)blockIdx.z * 3145728 : 0);
    int t = blockIdx.x;
    const void* src; ushort_t* dst; int Kw, Nw; long ioff;
    if (t < 192)      { src = aw;  dst = obase;           Kw = 512;  Nw = 1536; ioff = lay * 512L * 1536; }
    else if (t < 256) { t -= 192; src = pw;  dst = obase + 786432;  Kw = 512;  Nw = 512;  ioff = lay * 512L * 512; }
    else if (t < 512) { t -= 256; src = fw;  dst = obase + 1048576; Kw = 512;  Nw = 2048; ioff = lay * 512L * 2048; }
    else              { t -= 512; src = fpw; dst = obase + 2097152; Kw = 2048; Nw = 512;  ioff = lay * 2048L * 512; }
    int tn = Nw >> 6;
    int n0 = (t % tn) * 64, k0 = (t / tn) * 64;
    const int r = threadIdx.x >> 2, cq = (threadIdx.x & 3) * 16;
    size_t ii = ioff + (size_t)(k0 + r) * Nw + n0 + cq;
    if (isbf) {
        const ushort_t* sb = (const ushort_t*)src + ii;
        ushort_t tmp[16];
        *(uint4*)tmp = *(const uint4*)sb;
        *(uint4*)(tmp + 8) = *(const uint4*)(sb + 8);
#pragma unroll
        for (int j = 0; j < 16; ++j) tile[r][cq + j] = bf2f(tmp[j]);
    } else {
        const float* sf = (const float*)src + ii;
        *(float4*)&tile[r][cq]      = *(const float4*)sf;
        *(float4*)&tile[r][cq + 4]  = *(const float4*)(sf + 4);
        *(float4*)&tile[r][cq + 8]  = *(const float4*)(sf + 8);
        *(float4*)&tile[r][cq + 12] = *(const float4*)(sf + 12);
    }
    __syncthreads();
    const int kc = (threadIdx.x & 7) * 8;
#pragma unroll
    for (int j = 0; j < 2; ++j) {
        const int n = (threadIdx.x >> 3) + j * 32;
        unsigned pk[4];
#pragma unroll
        for (int i = 0; i < 4; ++i) {
            unsigned lo = f2bf(tile[kc + 2 * i][n]);
            unsigned hi = f2bf(tile[kc + 2 * i + 1][n]);
            pk[i] = lo | (hi << 16);
        }
        *(uint4*)(dst + (size_t)(n0 + n) * Kw + k0 + kc) = *(uint4*)pk;
    }
}

// ---------------- wte convert (zero-padded to VPAD rows) -----------------------
__global__ __launch_bounds__(256) void wconv_k(const void* __restrict__ in,
        ushort_t* __restrict__ out, int n, int nreal, const int* __restrict__ flag)
{
    int i = blockIdx.x * 256 + threadIdx.x;
    if (i >= n) return;
    ushort_t v = 0;
    if (i < nreal) v = (*flag) ? ((const ushort_t*)in)[i] : f2bf(((const float*)in)[i]);
    out[i] = v;
}

// ---------------- wide NT GEMM: 128x64 tile, BK=64, T14 prefetch, T1 swizzle ---
__global__ __launch_bounds__(256) void gemm_wide(const ushort_t* __restrict__ A,
        const ushort_t* __restrict__ Bt, int M, int N, int K,
        float* __restrict__ outF, ushort_t* __restrict__ outB,
        const float* __restrict__ res, int act)
{
    __shared__ ushort_t Al[128 * 72];
    __shared__ ushort_t Bl[64 * 72];
    const int tid = threadIdx.x;
    const int wave = tid >> 6, lane = tid & 63;
    const int quad = lane >> 4, l16 = lane & 15;
    int xl, yl; xcd_swz(xl, yl);
    const int m0 = yl * 128, n0 = xl * 64;
    const int ar = tid >> 1, ac = (tid & 1) * 32;
    const int br = tid >> 2, bc = (tid & 3) * 16;
    const ushort_t* Ag = A + (size_t)(m0 + ar) * K + ac;
    const ushort_t* Bg = Bt + (size_t)(n0 + br) * K + bc;
    f32x4 acc[2][4] = {};
    uint4 a0 = *(const uint4*)(Ag);
    uint4 a1 = *(const uint4*)(Ag + 8);
    uint4 a2 = *(const uint4*)(Ag + 16);
    uint4 a3 = *(const uint4*)(Ag + 24);
    uint4 b0 = *(const uint4*)(Bg);
    uint4 b1 = *(const uint4*)(Bg + 8);
    for (int k0 = 0; k0 < K; k0 += 64) {
        __syncthreads();
        *(uint4*)&Al[ar * 72 + ac]      = a0;
        *(uint4*)&Al[ar * 72 + ac + 8]  = a1;
        *(uint4*)&Al[ar * 72 + ac + 16] = a2;
        *(uint4*)&Al[ar * 72 + ac + 24] = a3;
        *(uint4*)&Bl[br * 72 + bc]     = b0;
        *(uint4*)&Bl[br * 72 + bc + 8] = b1;
        __syncthreads();
        if (k0 + 64 < K) {                      // prefetch: flies during MFMAs
            a0 = *(const uint4*)(Ag + k0 + 64);
            a1 = *(const uint4*)(Ag + k0 + 72);
            a2 = *(const uint4*)(Ag + k0 + 80);
            a3 = *(const uint4*)(Ag + k0 + 88);
            b0 = *(const uint4*)(Bg + k0 + 64);
            b1 = *(const uint4*)(Bg + k0 + 72);
        }
#pragma unroll
        for (int ks = 0; ks < 2; ++ks) {
            short8 af[2], bf[4];
#pragma unroll
            for (int mi = 0; mi < 2; ++mi)
                af[mi] = *(const short8*)&Al[(wave * 32 + mi * 16 + l16) * 72 + ks * 32 + quad * 8];
#pragma unroll
            for (int ni = 0; ni < 4; ++ni)
                bf[ni] = *(const short8*)&Bl[(ni * 16 + l16) * 72 + ks * 32 + quad * 8];
#pragma unroll
            for (int mi = 0; mi < 2; ++mi)
#pragma unroll
                for (int ni = 0; ni < 4; ++ni)
                    acc[mi][ni] = __builtin_amdgcn_mfma_f32_16x16x32_bf16(
                            af[mi], bf[ni], acc[mi][ni], 0, 0, 0);
        }
    }
#pragma unroll
    for (int mi = 0; mi < 2; ++mi) {
        const int rowb = m0 + wave * 32 + mi * 16 + quad * 4;
#pragma unroll
        for (int ni = 0; ni < 4; ++ni) {
            const int col = n0 + ni * 16 + l16;
#pragma unroll
            for (int r = 0; r < 4; ++r) {
                size_t o = (size_t)(rowb + r) * N + col;
                float v = acc[mi][ni][r];
                if (res) v += res[o];
                if (act) v = 0.5f * v * (1.0f + erff(v * 0.70710678118f));
                if (outF) outF[o] = v;
                else      outB[o] = f2bf(v);
            }
        }
    }
}

// ---------------- small NT GEMM (logits): T14 prefetch + T1 swizzle ------------
__global__ __launch_bounds__(256) void gemm_nt(const ushort_t* __restrict__ A,
        const ushort_t* __restrict__ Bt, int M, int N, int K,
        float* __restrict__ outF, ushort_t* __restrict__ outB, void* __restrict__ outD,
        const float* __restrict__ res, int act, const int* __restrict__ flag)
{
    __shared__ ushort_t Al[64 * 72];
    __shared__ ushort_t Bl[64 * 72];
    const int isbf = *flag;
    const int tid = threadIdx.x;
    const int wave = tid >> 6, lane = tid & 63;
    const int quad = lane >> 4, l16 = lane & 15;
    int xl, yl; xcd_swz(xl, yl);
    const int m0 = yl * 64, n0 = xl * 64;
    const int sr = tid >> 2, sc = (tid & 3) * 16;
    const bool bok = (n0 + sr) < N;
    const ushort_t* Ag = A + (size_t)(m0 + sr) * K + sc;
    const ushort_t* Bg = Bt + (size_t)(n0 + sr) * K + sc;
    f32x4 acc[4] = {};
    uint4 a0 = *(const uint4*)(Ag);
    uint4 a1 = *(const uint4*)(Ag + 8);
    uint4 b0 = make_uint4(0, 0, 0, 0), b1 = make_uint4(0, 0, 0, 0);
    if (bok) { b0 = *(const uint4*)(Bg); b1 = *(const uint4*)(Bg + 8); }
    for (int k0 = 0; k0 < K; k0 += 64) {
        __syncthreads();
        *(uint4*)&Al[sr * 72 + sc] = a0; *(uint4*)&Al[sr * 72 + sc + 8] = a1;
        *(uint4*)&Bl[sr * 72 + sc] = b0; *(uint4*)&Bl[sr * 72 + sc + 8] = b1;
        __syncthreads();
        if (k0 + 64 < K) {                      // prefetch: flies during MFMAs
            a0 = *(const uint4*)(Ag + k0 + 64);
            a1 = *(const uint4*)(Ag + k0 + 72);
            if (bok) {
                b0 = *(const uint4*)(Bg + k0 + 64);
                b1 = *(const uint4*)(Bg + k0 + 72);
            }
        }
#pragma unroll
        for (int kc = 0; kc < 2; ++kc) {
            short8 af = *(const short8*)&Al[(wave * 16 + l16) * 72 + kc * 32 + quad * 8];
#pragma unroll
            for (int nt = 0; nt < 4; ++nt) {
                short8 bf = *(const short8*)&Bl[(nt * 16 + l16) * 72 + kc * 32 + quad * 8];
                acc[nt] = __builtin_amdgcn_mfma_f32_16x16x32_bf16(af, bf, acc[nt], 0, 0, 0);
            }
        }
    }
    const int mb = m0 + wave * 16 + quad * 4;
#pragma unroll
    for (int nt = 0; nt < 4; ++nt) {
        int nn = n0 + nt * 16 + l16;
        if (nn >= N) continue;
#pragma unroll
        for (int r = 0; r < 4; ++r) {
            size_t o = (size_t)(mb + r) * N + nn;
            float v = acc[nt][r];
            if (res) v += res[o];
            if (act) v = 0.5f * v * (1.0f + erff(v * 0.70710678118f));
            if (outF)      outF[o] = v;
            else if (outB) outB[o] = f2bf(v);
            else if (isbf) ((ushort_t*)outD)[o] = f2bf(v);
            else           ((float*)outD)[o] = v;
        }
    }
}

// ---------------- split-K NT GEMM (proj/fcp): XCD-swizzled, atomicAdd ----------
// Requires grid (8,64,z). Logical (x,y,z) decoded so the 8 x-blocks sharing an
// A-panel sit at dispatch slots == group (mod 8) -> same XCD -> panel is
// fetched once into that XCD's L2. out must already hold the residual (xw).
__global__ __launch_bounds__(256) void gemm_sk(const ushort_t* __restrict__ A,
        const ushort_t* __restrict__ Bt, int M, int N, int K,
        float* __restrict__ out)
{
    __shared__ ushort_t Al[64 * 72];
    __shared__ ushort_t Bl[64 * 72];
    const int tid = threadIdx.x;
    const int wave = tid >> 6, lane = tid & 63;
    const int quad = lane >> 4, l16 = lane & 15;
    const int slot = ((int)blockIdx.z * (int)gridDim.y + (int)blockIdx.y) * 8
                   + (int)blockIdx.x;
    const int gl = (slot & 7) + 8 * (slot >> 6);
    const int xl = (slot >> 3) & 7;
    const int yl = gl & 63;
    const int zl = gl >> 6;
    const int m0 = yl * 64, n0 = xl * 64;
    const int kh = K / (int)gridDim.z, koff = zl * kh;
    const int sr = tid >> 2, sc = (tid & 3) * 16;
    const ushort_t* Ag = A + (size_t)(m0 + sr) * K + koff + sc;
    const ushort_t* Bg = Bt + (size_t)(n0 + sr) * K + koff + sc;
    f32x4 acc[4] = {};
    uint4 a0 = *(const uint4*)(Ag);
    uint4 a1 = *(const uint4*)(Ag + 8);
    uint4 b0 = *(const uint4*)(Bg);
    uint4 b1 = *(const uint4*)(Bg + 8);
    for (int k0 = 0; k0 < kh; k0 += 64) {
        __syncthreads();
        *(uint4*)&Al[sr * 72 + sc] = a0; *(uint4*)&Al[sr * 72 + sc + 8] = a1;
        *(uint4*)&Bl[sr * 72 + sc] = b0; *(uint4*)&Bl[sr * 72 + sc + 8] = b1;
        __syncthreads();
        if (k0 + 64 < kh) {                     // prefetch: flies during MFMAs
            a0 = *(const uint4*)(Ag + k0 + 64);
            a1 = *(const uint4*)(Ag + k0 + 72);
            b0 = *(const uint4*)(Bg + k0 + 64);
            b1 = *(const uint4*)(Bg + k0 + 72);
        }
#pragma unroll
        for (int kc = 0; kc < 2; ++kc) {
            short8 af = *(const short8*)&Al[(wave * 16 + l16) * 72 + kc * 32 + quad * 8];
#pragma unroll
            for (int nt = 0; nt < 4; ++nt) {
                short8 bf = *(const short8*)&Bl[(nt * 16 + l16) * 72 + kc * 32 + quad * 8];
                acc[nt] = __builtin_amdgcn_mfma_f32_16x16x32_bf16(af, bf, acc[nt], 0, 0, 0);
            }
        }
    }
    const int mb = m0 + wave * 16 + quad * 4;
#pragma unroll
    for (int nt = 0; nt < 4; ++nt) {
        const int nn = n0 + nt * 16 + l16;
#pragma unroll
        for (int r = 0; r < 4; ++r) {
            size_t o = (size_t)(mb + r) * N + nn;
            atomicAdd(&out[o], acc[nt][r]);
        }
    }
}

// ---------------- legacy GEMM (fallback) ---------------------------------------
__global__ __launch_bounds__(256) void gemm_k(const ushort_t* __restrict__ A,
        const void* __restrict__ B, long boff, int M, int N, int K, int bt,
        float* __restrict__ outF, ushort_t* __restrict__ outB, void* __restrict__ outD,
        const float* __restrict__ res, int act, const int* __restrict__ flag)
{
    __shared__ ushort_t Al[64 * 40];
    __shared__ ushort_t Bl[64 * 40];
    const int isbf = *flag;
    const int tid = threadIdx.x;
    const int wave = tid >> 6, lane = tid & 63;
    const int quad = lane >> 4, l16 = lane & 15;
    const int m0 = blockIdx.y * 64, n0 = blockIdx.x * 64;
    const int sr = tid >> 2, sc = (tid & 3) * 8;
    const int kr = tid >> 3, nc = (tid & 7) * 8;
    f32x4 acc[4] = {};
    const bool bok = (n0 + sr) < N;
    const ushort_t* Ag = A + (size_t)(m0 + sr) * K + sc;
    const ushort_t* Bb = (const ushort_t*)B + boff;
    const float*    Bf = (const float*)B + boff;
    const size_t i1 = (size_t)(n0 + sr) * K + sc;
    const size_t i0 = (size_t)kr * N + n0 + nc;
    for (int k0 = 0; k0 < K; k0 += 32) {
        uint4 av = *(const uint4*)(Ag + k0);
        ushort_t b8[8] = {0, 0, 0, 0, 0, 0, 0, 0};
        size_t bi = bt ? (i1 + k0) : (i0 + (size_t)k0 * N);
        if (!bt || bok) {
            if (isbf) *(uint4*)b8 = *(const uint4*)(Bb + bi);
            else {
                float4 f0 = *(const float4*)(Bf + bi);
                float4 f1 = *(const float4*)(Bf + bi + 4);
                b8[0] = f2bf(f0.x); b8[1] = f2bf(f0.y); b8[2] = f2bf(f0.z); b8[3] = f2bf(f0.w);
                b8[4] = f2bf(f1.x); b8[5] = f2bf(f1.y); b8[6] = f2bf(f1.z); b8[7] = f2bf(f1.w);
            }
        }
        __syncthreads();
        *(uint4*)&Al[sr * 40 + sc] = av;
        if (bt) *(uint4*)&Bl[sr * 40 + sc] = *(uint4*)b8;
        else {
#pragma unroll
            for (int i = 0; i < 8; ++i) Bl[(nc + i) * 40 + kr] = b8[i];
        }
        __syncthreads();
        short8 af = *(const short8*)&Al[(wave * 16 + l16) * 40 + quad * 8];
#pragma unroll
        for (int nt = 0; nt < 4; ++nt) {
            short8 bf = *(const short8*)&Bl[(nt * 16 + l16) * 40 + quad * 8];
            acc[nt] = __builtin_amdgcn_mfma_f32_16x16x32_bf16(af, bf, acc[nt], 0, 0, 0);
        }
    }
    const int mb = m0 + wave * 16 + quad * 4;
#pragma unroll
    for (int nt = 0; nt < 4; ++nt) {
        int nn = n0 + nt * 16 + l16;
        if (nn >= N) continue;
#pragma unroll
        for (int r = 0; r < 4; ++r) {
            size_t o = (size_t)(mb + r) * N + nn;
            float v = acc[nt][r];
            if (res) v += res[o];
            if (act) v = 0.5f * v * (1.0f + erff(v * 0.70710678118f));
            if (outF)      outF[o] = v;
            else if (outB) outB[o] = f2bf(v);
            else if (isbf) ((ushort_t*)outD)[o] = f2bf(v);
            else           ((float*)outD)[o] = v;
        }
    }
}

// ---------------- flash attention v6: in-reg P + setprio + T1 swizzle ----------
__global__ __launch_bounds__(256) void attn_k(const ushort_t* __restrict__ qkv,
        ushort_t* __restrict__ y)
{
    __shared__ ushort_t Kl[64 * 72];
    __shared__ ushort_t Vt[64 * 72];
    const int tid = threadIdx.x, wave = tid >> 6, lane = tid & 63;
    const int quad = lane >> 4, l16 = lane & 15;
    int xl, yl; xcd_swz(xl, yl);        // all q-tiles of one (b,h) on one XCD
    const int qt = (int)gridDim.x - 1 - xl;   // ascending slots -> long qt first
    const int b = yl >> 3, h = yl & 7;
    const int q0b = qt * 64;
    const int q0w = q0b + wave * 16;
    const size_t rstr = 3 * EMB;
    const ushort_t* qbase = qkv + ((size_t)(b * TS) + q0w + l16) * rstr + h * 64;
    short8 qf0, qf1;
    {   // load Q and pre-scale by 1/8 (exact in bf16)
        ushort_t q0[8], q1[8];
        *(uint4*)q0 = *(const uint4*)(qbase + quad * 8);
        *(uint4*)q1 = *(const uint4*)(qbase + 32 + quad * 8);
#pragma unroll
        for (int i = 0; i < 8; ++i) {
            qf0[i] = (short)f2bf(bf2f(q0[i]) * 0.125f);
            qf1[i] = (short)f2bf(bf2f(q1[i]) * 0.125f);
        }
    }
    f32x4 O[4] = {};
    float lsum = 0.f;
    const int sk = tid >> 2, sdc = (tid & 3) * 16;
    const int vp = tid >> 3, vdc = (tid & 7) * 8;
    const int vsh = 16 * ((tid & 7) & 3);
    // sigma(2*vp): kc=vp>>4, qhat=(vp>>1)&3, ntlow=(vp>>3)&1, r=2*(vp&1)
    const int p0 = ((vp >> 4) << 5) | (((vp >> 1) & 3) << 3)
                 | (((vp >> 3) & 1) << 2) | ((vp & 1) << 1);
    const int vcol = (p0 + vsh) & 63;
    const ushort_t* kbase = qkv + ((size_t)(b * TS) + sk) * rstr + EMB + h * 64 + sdc;
    const ushort_t* vbase = qkv + ((size_t)(b * TS) + 2 * vp) * rstr + 2 * EMB + h * 64 + vdc;
    uint4 kv0 = *(const uint4*)(kbase);
    uint4 kv1 = *(const uint4*)(kbase + 8);
    uint4 vv0 = *(const uint4*)(vbase);
    uint4 vv1 = *(const uint4*)(vbase + rstr);
    for (int kt = 0; kt <= qt; ++kt) {
        __syncthreads();                 // all waves done reading Kl/Vt (prev)
        *(uint4*)&Kl[sk * 72 + sdc]     = kv0;
        *(uint4*)&Kl[sk * 72 + sdc + 8] = kv1;
        {
            ushort_t v0[8], v1[8];
            *(uint4*)v0 = vv0; *(uint4*)v1 = vv1;
#pragma unroll
            for (int i = 0; i < 8; ++i) {
                unsigned pk = (unsigned)v0[i] | ((unsigned)v1[i] << 16);
                *(unsigned*)&Vt[(vdc + i) * 72 + vcol] = pk;
            }
        }
        __syncthreads();                 // tile kt visible
        if (kt < qt) {                   // prefetch kt+1: flies during compute
            const size_t off = (size_t)(kt + 1) * 64 * rstr;
            kv0 = *(const uint4*)(kbase + off);
            kv1 = *(const uint4*)(kbase + off + 8);
            vv0 = *(const uint4*)(vbase + off);
            vv1 = *(const uint4*)(vbase + off + rstr);
        }
        const bool diag = (kt == qt);
        f32x4 S[4] = {};
        __builtin_amdgcn_s_setprio(1);
#pragma unroll
        for (int nt = 0; nt < 4; ++nt) {
            if (diag && nt > wave) continue;
            short8 kf0 = *(const short8*)&Kl[(nt * 16 + l16) * 72 + quad * 8];
            short8 kf1 = *(const short8*)&Kl[(nt * 16 + l16) * 72 + 32 + quad * 8];
            S[nt] = __builtin_amdgcn_mfma_f32_16x16x32_bf16(kf0, qf0, S[nt], 0, 0, 0);
            S[nt] = __builtin_amdgcn_mfma_f32_16x16x32_bf16(kf1, qf1, S[nt], 0, 0, 0);
        }
        __builtin_amdgcn_s_setprio(0);
        unsigned pk[4][2];
#pragma unroll
        for (int nt = 0; nt < 4; ++nt) {
            float p[4];
#pragma unroll
            for (int r = 0; r < 4; ++r) {
                bool live = !diag || (nt * 16 + quad * 4 + r <= wave * 16 + l16);
                p[r] = live ? __expf(S[nt][r]) : 0.f;
                lsum += p[r];
            }
            pk[nt][0] = (unsigned)f2bf(p[0]) | ((unsigned)f2bf(p[1]) << 16);
            pk[nt][1] = (unsigned)f2bf(p[2]) | ((unsigned)f2bf(p[3]) << 16);
        }
        __builtin_amdgcn_s_setprio(1);
#pragma unroll
        for (int kc = 0; kc < 2; ++kc) {
            unsigned pw[4] = {pk[2 * kc][0], pk[2 * kc][1],
                              pk[2 * kc + 1][0], pk[2 * kc + 1][1]};
            short8 pf = *(const short8*)pw;
#pragma unroll
            for (int dt = 0; dt < 4; ++dt) {
                int d = dt * 16 + l16;
                int sh = ((2 * dt + (l16 >> 3)) & 3) * 16;
                int col = (kc * 32 + quad * 8 + sh) & 63;
                short8 vf = *(const short8*)&Vt[d * 72 + col];
                O[dt] = __builtin_amdgcn_mfma_f32_16x16x32_bf16(vf, pf, O[dt], 0, 0, 0);
            }
        }
        __builtin_amdgcn_s_setprio(0);
    }
    lsum += __shfl_xor(lsum, 16, 64);
    lsum += __shfl_xor(lsum, 32, 64);
    const float inv = 1.0f / lsum;
    ushort_t* yb = y + ((size_t)(b * TS) + q0w + l16) * EMB + h * 64 + quad * 4;
#pragma unroll
    for (int dt = 0; dt < 4; ++dt) {
        unsigned ow[2];
        ow[0] = (unsigned)f2bf(O[dt][0] * inv) | ((unsigned)f2bf(O[dt][1] * inv) << 16);
        ow[1] = (unsigned)f2bf(O[dt][2] * inv) | ((unsigned)f2bf(O[dt][3] * inv) << 16);
        *(uint2*)(yb + dt * 16) = *(uint2*)ow;
    }
}

// ---------------- host ---------------------------------------------------------
extern "C" void kernel_launch(void* const* d_in, const int* in_sizes, int n_in,
                              void* d_out, int out_size, void* d_ws, size_t ws_size,
                              hipStream_t stream)
{
    const int*  idx    = (const int*)d_in[0];
    const void* wte    = d_in[1];
    const void* wpe    = d_in[2];
    const void* attn_w = d_in[3];   // [L,512,1536]
    const void* proj_w = d_in[4];   // [L,512,512]
    const void* fc_w   = d_in[5];   // [L,512,2048]
    const void* fcp_w  = d_in[6];   // [L,2048,512]
    const void* ln1_w  = d_in[7];
    const void* ln2_w  = d_in[8];
    const void* lnf_w  = d_in[9];

    const size_t sz_xw    = (size_t)NTOK * EMB * 4;
    const size_t sz_hbf   = (size_t)NTOK * EMB * 2;
    const size_t sz_big   = (size_t)NTOK * 2048 * 2;
    const size_t sz_wteb  = (size_t)VPAD * EMB * 2;
    const size_t sz_wbuf1 = (size_t)3145728 * 2;
    const size_t need_legacy = 256 + sz_xw + sz_hbf + sz_big;
    const size_t need_fast   = need_legacy + sz_wteb + sz_wbuf1;
    const size_t need_all    = need_legacy + sz_wteb + NL * sz_wbuf1;   // ~80 MB

    if (ws_size < need_legacy) {
        sentinel_k<<<(out_size + 255) / 256, 256, 0, stream>>>((ushort_t*)d_out, out_size);
        return;
    }
    int* flag = (int*)d_ws;
    char* p = (char*)d_ws + 256;
    float*    xw  = (float*)p;    p += sz_xw;
    ushort_t* hbf = (ushort_t*)p; p += sz_hbf;
    ushort_t* big = (ushort_t*)p; p += sz_big;

    detect_k<<<1, 64, 0, stream>>>((const ushort_t*)wte, flag);
    embed_k<<<NTOK, 256, 0, stream>>>(idx, wte, wpe, xw, flag);

    if (ws_size >= need_fast) {
        ushort_t* wteb = (ushort_t*)p; p += sz_wteb;
        ushort_t* wbuf = (ushort_t*)p;
        const bool allw = (ws_size >= need_all);
        wconv_k<<<(VPAD * EMB + 255) / 256, 256, 0, stream>>>(wte, wteb,
                VPAD * EMB, VOCAB * EMB, flag);
        if (allw)
            wtrans_k<<<dim3(768, 1, NL), 256, 0, stream>>>(attn_w, proj_w, fc_w, fcp_w,
                    -1, wbuf, flag);
        for (int l = 0; l < NL; ++l) {
            ushort_t* wb = allw ? (wbuf + (size_t)l * 3145728) : wbuf;
            if (!allw)
                wtrans_k<<<dim3(768, 1, 1), 256, 0, stream>>>(attn_w, proj_w, fc_w, fcp_w,
                        (long)l, wbuf, flag);
            ln_k<<<NTOK / 4, 256, 0, stream>>>(xw, ln1_w, (long)l * EMB, hbf, flag);
            gemm_wide<<<dim3(24, 32), 256, 0, stream>>>(hbf, wb,
                    NTOK, 1536, 512, nullptr, big, nullptr, 0);
            attn_k<<<dim3(16, 32), 256, 0, stream>>>(big, hbf);
            gemm_sk<<<dim3(8, 64, 2), 256, 0, stream>>>(hbf, wb + 786432,
                    NTOK, 512, 512, xw);
            ln_k<<<NTOK / 4, 256, 0, stream>>>(xw, ln2_w, (long)l * EMB, hbf, flag);
            gemm_wide<<<dim3(32, 32), 256, 0, stream>>>(hbf, wb + 1048576,
                    NTOK, 2048, 512, nullptr, big, nullptr, 1 /*gelu*/);
            gemm_sk<<<dim3(8, 64, 2), 256, 0, stream>>>(big, wb + 2097152,
                    NTOK, 512, 2048, xw);
        }
        ln_k<<<NTOK / 4, 256, 0, stream>>>(xw, lnf_w, 0, hbf, flag);
        gemm_nt<<<dim3(6, 64), 256, 0, stream>>>(hbf, wteb,
                NTOK, VOCAB, 512, nullptr, nullptr, d_out, nullptr, 0, flag);
    } else {
        for (int l = 0; l < NL; ++l) {
            ln_k<<<NTOK / 4, 256, 0, stream>>>(xw, ln1_w, (long)l * EMB, hbf, flag);
            gemm_k<<<dim3(24, 64), 256, 0, stream>>>(hbf, attn_w, (long)l * 512 * 1536,
                    NTOK, 1536, 512, 0, nullptr, big, nullptr, nullptr, 0, flag);
            attn_k<<<dim3(16, 32), 256, 0, stream>>>(big, hbf);
            gemm_k<<<dim3(8, 64), 256, 0, stream>>>(hbf, proj_w, (long)l * 512 * 512,
                    NTOK, 512, 512, 0, xw, nullptr, nullptr, xw, 0, flag);
            ln_k<<<NTOK / 4, 256, 0, stream>>>(xw, ln2_w, (long)l * EMB, hbf, flag);
            gemm_k<<<dim3(32, 64), 256, 0, stream>>>(hbf, fc_w, (long)l * 512 * 2048,
                    NTOK, 2048, 512, 0, nullptr, big, nullptr, nullptr, 1, flag);
            gemm_k<<<dim3(8, 64), 256, 0, stream>>>(big, fcp_w, (long)l * 2048 * 512,
                    NTOK, 512, 2048, 0, xw, nullptr, nullptr, xw, 0, flag);
        }
        ln_k<<<NTOK / 4, 256, 0, stream>>>(xw, lnf_w, 0, hbf, flag);
        gemm_k<<<dim3(6, 64), 256, 0, stream>>>(hbf, wte, 0,
                NTOK, VOCAB, 512, 1, nullptr, nullptr, d_out, nullptr, 0, flag);
    }
}

// Round 13
// 986.714 us; speedup vs baseline: 1.0211x; 1.0211x over previous
//
#include <hip/hip_runtime.h>

// GPT forward, MI355X gfx950.
// Shapes: V=371 E=512 H=8 L=8 B=4 T=1024 D=64, N=B*T=4096.
// Inputs float32 (runtime-detected, bf16 supported); output matches input fmt.
// r22: revert proj to gemm_nt (r21 A/B: proj split-K at kh=256 loses +21us —
// split-K pays only at kh>=1024 on this problem; fcp z=2 stays). wtrans v4:
// each block processes a k-PAIR (two 64x64 tiles, same LDS, halved grid
// 768->384) — wtrans was per-block-overhead bound (41us, 7% VALU, 30% HBM,
// 0 MFMA: 6144 tiny blocks). Everything else = r20 (T1 swizzle everywhere,
// attn v6 in-reg P + setprio, fcp sk z=2 swizzled).

#define VOCAB 371
#define VPAD  384
#define EMB   512
#define NH    8
#define NL    8
#define TS    1024
#define NTOK  4096
#define NEG_INF (-1e30f)

typedef unsigned short ushort_t;
typedef __attribute__((ext_vector_type(8))) short short8;
typedef __attribute__((ext_vector_type(4))) float f32x4;

__device__ inline float bf2f(ushort_t b) {
    unsigned int u = ((unsigned int)b) << 16;
    float f; __builtin_memcpy(&f, &u, 4); return f;
}
__device__ inline ushort_t f2bf(float f) {
    unsigned int u; __builtin_memcpy(&u, &f, 4);
    u = (u + 0x7fff + ((u >> 16) & 1)) >> 16;   // RNE
    return (ushort_t)u;
}

// T1 XCD swizzle: co-locate all x-blocks of a y-group on one XCD.
// Requires gridDim.y % 8 == 0. Returns (xl, yl).
__device__ inline void xcd_swz(int& xl, int& yl) {
    const int slot = (int)blockIdx.y * (int)gridDim.x + (int)blockIdx.x;
    const int xcd = slot & 7, idx = slot >> 3;
    const int ypg = (int)gridDim.y >> 3;
    yl = xcd + 8 * (idx % ypg);
    xl = idx / ypg;
}

// ---------------- dtype probe ---------------------------------------------------
__global__ __launch_bounds__(64) void detect_k(const ushort_t* __restrict__ w,
        int* __restrict__ flag)
{
    int i = threadIdx.x;
    float v = bf2f(w[2 * i]);
    bool ok = (__builtin_fabsf(v) <= 4.0f);
    unsigned long long m = __ballot(ok);
    if (i == 0) flag[0] = (__popcll(m) >= 56) ? 1 : 0;   // 1 = bf16, 0 = float32
}

// ---------------- ws-too-small sentinel ----------------------------------------
__global__ __launch_bounds__(256) void sentinel_k(ushort_t* __restrict__ out, int n)
{
    int i = blockIdx.x * 256 + threadIdx.x;
    if (i < n) out[i] = 0x447A;
}

// ---------------- embedding ----------------------------------------------------
__global__ __launch_bounds__(256) void embed_k(const int* __restrict__ idx,
        const void* __restrict__ wte, const void* __restrict__ wpe,
        float* __restrict__ x, const int* __restrict__ flag)
{
    int n = blockIdx.x, tid = threadIdx.x;
    int t = n & (TS - 1);
    int v = idx[n];
    size_t o = (size_t)n * EMB;
    float a0, a1, b0, b1;
    if (*flag) {
        const ushort_t* te = (const ushort_t*)wte; const ushort_t* pe = (const ushort_t*)wpe;
        a0 = bf2f(te[v * EMB + tid]); a1 = bf2f(te[v * EMB + 256 + tid]);
        b0 = bf2f(pe[t * EMB + tid]); b1 = bf2f(pe[t * EMB + 256 + tid]);
    } else {
        const float* te = (const float*)wte; const float* pe = (const float*)wpe;
        a0 = te[v * EMB + tid]; a1 = te[v * EMB + 256 + tid];
        b0 = pe[t * EMB + tid]; b1 = pe[t * EMB + 256 + tid];
    }
    x[o + tid] = a0 + b0;
    x[o + 256 + tid] = a1 + b1;
}

// ---------------- layernorm v2: one wave per row, no barriers ------------------
__global__ __launch_bounds__(256) void ln_k(const float* __restrict__ x,
        const void* __restrict__ w, long woff, ushort_t* __restrict__ out,
        const int* __restrict__ flag)
{
    const int row = blockIdx.x * 4 + (threadIdx.x >> 6);
    const int lane = threadIdx.x & 63;
    const float* xr = x + (size_t)row * EMB + lane * 8;
    float4 f0 = *(const float4*)xr;
    float4 f1 = *(const float4*)(xr + 4);
    float v[8] = {f0.x, f0.y, f0.z, f0.w, f1.x, f1.y, f1.z, f1.w};
    float s = ((v[0] + v[1]) + (v[2] + v[3])) + ((v[4] + v[5]) + (v[6] + v[7]));
#pragma unroll
    for (int off = 32; off > 0; off >>= 1) s += __shfl_xor(s, off, 64);
    float mean = s * (1.0f / EMB);
    float s2 = 0.f;
#pragma unroll
    for (int j = 0; j < 8; ++j) { v[j] -= mean; s2 += v[j] * v[j]; }
#pragma unroll
    for (int off = 32; off > 0; off >>= 1) s2 += __shfl_xor(s2, off, 64);
    float rs = rsqrtf(s2 * (1.0f / EMB) + 1e-5f);
    float g[8];
    if (*flag) {
        const ushort_t* wb = (const ushort_t*)w + woff + lane * 8;
        ushort_t tmp[8];
        *(uint4*)tmp = *(const uint4*)wb;
#pragma unroll
        for (int j = 0; j < 8; ++j) g[j] = bf2f(tmp[j]);
    } else {
        const float* wf = (const float*)w + woff + lane * 8;
        float4 g0 = *(const float4*)wf;
        float4 g1 = *(const float4*)(wf + 4);
        g[0] = g0.x; g[1] = g0.y; g[2] = g0.z; g[3] = g0.w;
        g[4] = g1.x; g[5] = g1.y; g[6] = g1.z; g[7] = g1.w;
    }
    ushort_t ob[8];
#pragma unroll
    for (int j = 0; j < 8; ++j) ob[j] = f2bf(v[j] * rs * g[j]);
    *(uint4*)(out + (size_t)row * EMB + lane * 8) = *(uint4*)ob;
}

// ---------------- weight transpose v4: [K,N] dtype -> bf16 [N,K], k-pairs ------
// Each block handles TWO 64x64 tiles (same n0, k0 and k0+64) to amortize
// per-block overhead; grid halves to 384 x NL. Segments (per layer):
// attn 24n*4kp=96, proj 8n*4kp=32, fc 32n*4kp=128, fcp 8n*16kp=128.
__global__ __launch_bounds__(256) void wtrans_k(const void* __restrict__ aw,
        const void* __restrict__ pw, const void* __restrict__ fw,
        const void* __restrict__ fpw, long l, ushort_t* __restrict__ wbuf,
        const int* __restrict__ flag)
{
    __shared__ float tile[64][65];
    const int isbf = *flag;
    long lay = (l < 0) ? (long)blockIdx.z : l;
    ushort_t* obase = wbuf + ((l < 0) ? (size_t)blockIdx.z * 3145728 : 0);
    int t = blockIdx.x;
    const void* src; ushort_t* dst; int Kw, Nw; long ioff;
    if (t < 96)       { src = aw;  dst = obase;           Kw = 512;  Nw = 1536; ioff = lay * 512L * 1536; }
    else if (t < 128) { t -= 96;  src = pw;  dst = obase + 786432;  Kw = 512;  Nw = 512;  ioff = lay * 512L * 512; }
    else if (t < 256) { t -= 128; src = fw;  dst = obase + 1048576; Kw = 512;  Nw = 2048; ioff = lay * 512L * 2048; }
    else              { t -= 256; src = fpw; dst = obase + 2097152; Kw = 2048; Nw = 512;  ioff = lay * 2048L * 512; }
    int tn = Nw >> 6;
    int n0 = (t % tn) * 64;
    const int kbase = (t / tn) * 128;
    const int r = threadIdx.x >> 2, cq = (threadIdx.x & 3) * 16;
    const int kc = (threadIdx.x & 7) * 8;
#pragma unroll
    for (int kk = 0; kk < 2; ++kk) {
        const int k0 = kbase + kk * 64;
        if (kk) __syncthreads();              // prev round's readers done
        size_t ii = ioff + (size_t)(k0 + r) * Nw + n0 + cq;
        if (isbf) {
            const ushort_t* sb = (const ushort_t*)src + ii;
            ushort_t tmp[16];
            *(uint4*)tmp = *(const uint4*)sb;
            *(uint4*)(tmp + 8) = *(const uint4*)(sb + 8);
#pragma unroll
            for (int j = 0; j < 16; ++j) tile[r][cq + j] = bf2f(tmp[j]);
        } else {
            const float* sf = (const float*)src + ii;
            *(float4*)&tile[r][cq]      = *(const float4*)sf;
            *(float4*)&tile[r][cq + 4]  = *(const float4*)(sf + 4);
            *(float4*)&tile[r][cq + 8]  = *(const float4*)(sf + 8);
            *(float4*)&tile[r][cq + 12] = *(const float4*)(sf + 12);
        }
        __syncthreads();
#pragma unroll
        for (int j = 0; j < 2; ++j) {
            const int n = (threadIdx.x >> 3) + j * 32;
            unsigned pk[4];
#pragma unroll
            for (int i = 0; i < 4; ++i) {
                unsigned lo = f2bf(tile[kc + 2 * i][n]);
                unsigned hi = f2bf(tile[kc + 2 * i + 1][n]);
                pk[i] = lo | (hi << 16);
            }
            *(uint4*)(dst + (size_t)(n0 + n) * Kw + k0 + kc) = *(uint4*)pk;
        }
    }
}

// ---------------- wte convert (zero-padded to VPAD rows) -----------------------
__global__ __launch_bounds__(256) void wconv_k(const void* __restrict__ in,
        ushort_t* __restrict__ out, int n, int nreal, const int* __restrict__ flag)
{
    int i = blockIdx.x * 256 + threadIdx.x;
    if (i >= n) return;
    ushort_t v = 0;
    if (i < nreal) v = (*flag) ? ((const ushort_t*)in)[i] : f2bf(((const float*)in)[i]);
    out[i] = v;
}

// ---------------- wide NT GEMM: 128x64 tile, BK=64, T14 prefetch, T1 swizzle ---
__global__ __launch_bounds__(256) void gemm_wide(const ushort_t* __restrict__ A,
        const ushort_t* __restrict__ Bt, int M, int N, int K,
        float* __restrict__ outF, ushort_t* __restrict__ outB,
        const float* __restrict__ res, int act)
{
    __shared__ ushort_t Al[128 * 72];
    __shared__ ushort_t Bl[64 * 72];
    const int tid = threadIdx.x;
    const int wave = tid >> 6, lane = tid & 63;
    const int quad = lane >> 4, l16 = lane & 15;
    int xl, yl; xcd_swz(xl, yl);
    const int m0 = yl * 128, n0 = xl * 64;
    const int ar = tid >> 1, ac = (tid & 1) * 32;
    const int br = tid >> 2, bc = (tid & 3) * 16;
    const ushort_t* Ag = A + (size_t)(m0 + ar) * K + ac;
    const ushort_t* Bg = Bt + (size_t)(n0 + br) * K + bc;
    f32x4 acc[2][4] = {};
    uint4 a0 = *(const uint4*)(Ag);
    uint4 a1 = *(const uint4*)(Ag + 8);
    uint4 a2 = *(const uint4*)(Ag + 16);
    uint4 a3 = *(const uint4*)(Ag + 24);
    uint4 b0 = *(const uint4*)(Bg);
    uint4 b1 = *(const uint4*)(Bg + 8);
    for (int k0 = 0; k0 < K; k0 += 64) {
        __syncthreads();
        *(uint4*)&Al[ar * 72 + ac]      = a0;
        *(uint4*)&Al[ar * 72 + ac + 8]  = a1;
        *(uint4*)&Al[ar * 72 + ac + 16] = a2;
        *(uint4*)&Al[ar * 72 + ac + 24] = a3;
        *(uint4*)&Bl[br * 72 + bc]     = b0;
        *(uint4*)&Bl[br * 72 + bc + 8] = b1;
        __syncthreads();
        if (k0 + 64 < K) {                      // prefetch: flies during MFMAs
            a0 = *(const uint4*)(Ag + k0 + 64);
            a1 = *(const uint4*)(Ag + k0 + 72);
            a2 = *(const uint4*)(Ag + k0 + 80);
            a3 = *(const uint4*)(Ag + k0 + 88);
            b0 = *(const uint4*)(Bg + k0 + 64);
            b1 = *(const uint4*)(Bg + k0 + 72);
        }
#pragma unroll
        for (int ks = 0; ks < 2; ++ks) {
            short8 af[2], bf[4];
#pragma unroll
            for (int mi = 0; mi < 2; ++mi)
                af[mi] = *(const short8*)&Al[(wave * 32 + mi * 16 + l16) * 72 + ks * 32 + quad * 8];
#pragma unroll
            for (int ni = 0; ni < 4; ++ni)
                bf[ni] = *(const short8*)&Bl[(ni * 16 + l16) * 72 + ks * 32 + quad * 8];
#pragma unroll
            for (int mi = 0; mi < 2; ++mi)
#pragma unroll
                for (int ni = 0; ni < 4; ++ni)
                    acc[mi][ni] = __builtin_amdgcn_mfma_f32_16x16x32_bf16(
                            af[mi], bf[ni], acc[mi][ni], 0, 0, 0);
        }
    }
#pragma unroll
    for (int mi = 0; mi < 2; ++mi) {
        const int rowb = m0 + wave * 32 + mi * 16 + quad * 4;
#pragma unroll
        for (int ni = 0; ni < 4; ++ni) {
            const int col = n0 + ni * 16 + l16;
#pragma unroll
            for (int r = 0; r < 4; ++r) {
                size_t o = (size_t)(rowb + r) * N + col;
                float v = acc[mi][ni][r];
                if (res) v += res[o];
                if (act) v = 0.5f * v * (1.0f + erff(v * 0.70710678118f));
                if (outF) outF[o] = v;
                else      outB[o] = f2bf(v);
            }
        }
    }
}

// ---------------- small NT GEMM (proj/logits): T14 prefetch + T1 swizzle -------
__global__ __launch_bounds__(256) void gemm_nt(const ushort_t* __restrict__ A,
        const ushort_t* __restrict__ Bt, int M, int N, int K,
        float* __restrict__ outF, ushort_t* __restrict__ outB, void* __restrict__ outD,
        const float* __restrict__ res, int act, const int* __restrict__ flag)
{
    __shared__ ushort_t Al[64 * 72];
    __shared__ ushort_t Bl[64 * 72];
    const int isbf = *flag;
    const int tid = threadIdx.x;
    const int wave = tid >> 6, lane = tid & 63;
    const int quad = lane >> 4, l16 = lane & 15;
    int xl, yl; xcd_swz(xl, yl);
    const int m0 = yl * 64, n0 = xl * 64;
    const int sr = tid >> 2, sc = (tid & 3) * 16;
    const bool bok = (n0 + sr) < N;
    const ushort_t* Ag = A + (size_t)(m0 + sr) * K + sc;
    const ushort_t* Bg = Bt + (size_t)(n0 + sr) * K + sc;
    f32x4 acc[4] = {};
    uint4 a0 = *(const uint4*)(Ag);
    uint4 a1 = *(const uint4*)(Ag + 8);
    uint4 b0 = make_uint4(0, 0, 0, 0), b1 = make_uint4(0, 0, 0, 0);
    if (bok) { b0 = *(const uint4*)(Bg); b1 = *(const uint4*)(Bg + 8); }
    for (int k0 = 0; k0 < K; k0 += 64) {
        __syncthreads();
        *(uint4*)&Al[sr * 72 + sc] = a0; *(uint4*)&Al[sr * 72 + sc + 8] = a1;
        *(uint4*)&Bl[sr * 72 + sc] = b0; *(uint4*)&Bl[sr * 72 + sc + 8] = b1;
        __syncthreads();
        if (k0 + 64 < K) {                      // prefetch: flies during MFMAs
            a0 = *(const uint4*)(Ag + k0 + 64);
            a1 = *(const uint4*)(Ag + k0 + 72);
            if (bok) {
                b0 = *(const uint4*)(Bg + k0 + 64);
                b1 = *(const uint4*)(Bg + k0 + 72);
            }
        }
#pragma unroll
        for (int kc = 0; kc < 2; ++kc) {
            short8 af = *(const short8*)&Al[(wave * 16 + l16) * 72 + kc * 32 + quad * 8];
#pragma unroll
            for (int nt = 0; nt < 4; ++nt) {
                short8 bf = *(const short8*)&Bl[(nt * 16 + l16) * 72 + kc * 32 + quad * 8];
                acc[nt] = __builtin_amdgcn_mfma_f32_16x16x32_bf16(af, bf, acc[nt], 0, 0, 0);
            }
        }
    }
    const int mb = m0 + wave * 16 + quad * 4;
#pragma unroll
    for (int nt = 0; nt < 4; ++nt) {
        int nn = n0 + nt * 16 + l16;
        if (nn >= N) continue;
#pragma unroll
        for (int r = 0; r < 4; ++r) {
            size_t o = (size_t)(mb + r) * N + nn;
            float v = acc[nt][r];
            if (res) v += res[o];
            if (act) v = 0.5f * v * (1.0f + erff(v * 0.70710678118f));
            if (outF)      outF[o] = v;
            else if (outB) outB[o] = f2bf(v);
            else if (isbf) ((ushort_t*)outD)[o] = f2bf(v);
            else           ((float*)outD)[o] = v;
        }
    }
}

// ---------------- split-K NT GEMM (fcp): XCD-swizzled, atomicAdd ---------------
// Requires grid (8,64,z). Logical (x,y,z) decoded so the 8 x-blocks sharing an
// A-panel sit at dispatch slots == group (mod 8) -> same XCD -> panel is
// fetched once into that XCD's L2. out must already hold the residual (xw).
__global__ __launch_bounds__(256) void gemm_sk(const ushort_t* __restrict__ A,
        const ushort_t* __restrict__ Bt, int M, int N, int K,
        float* __restrict__ out)
{
    __shared__ ushort_t Al[64 * 72];
    __shared__ ushort_t Bl[64 * 72];
    const int tid = threadIdx.x;
    const int wave = tid >> 6, lane = tid & 63;
    const int quad = lane >> 4, l16 = lane & 15;
    const int slot = ((int)blockIdx.z * (int)gridDim.y + (int)blockIdx.y) * 8
                   + (int)blockIdx.x;
    const int gl = (slot & 7) + 8 * (slot >> 6);
    const int xl = (slot >> 3) & 7;
    const int yl = gl & 63;
    const int zl = gl >> 6;
    const int m0 = yl * 64, n0 = xl * 64;
    const int kh = K / (int)gridDim.z, koff = zl * kh;
    const int sr = tid >> 2, sc = (tid & 3) * 16;
    const ushort_t* Ag = A + (size_t)(m0 + sr) * K + koff + sc;
    const ushort_t* Bg = Bt + (size_t)(n0 + sr) * K + koff + sc;
    f32x4 acc[4] = {};
    uint4 a0 = *(const uint4*)(Ag);
    uint4 a1 = *(const uint4*)(Ag + 8);
    uint4 b0 = *(const uint4*)(Bg);
    uint4 b1 = *(const uint4*)(Bg + 8);
    for (int k0 = 0; k0 < kh; k0 += 64) {
        __syncthreads();
        *(uint4*)&Al[sr * 72 + sc] = a0; *(uint4*)&Al[sr * 72 + sc + 8] = a1;
        *(uint4*)&Bl[sr * 72 + sc] = b0; *(uint4*)&Bl[sr * 72 + sc + 8] = b1;
        __syncthreads();
        if (k0 + 64 < kh) {                     // prefetch: flies during MFMAs
            a0 = *(const uint4*)(Ag + k0 + 64);
            a1 = *(const uint4*)(Ag + k0 + 72);
            b0 = *(const uint4*)(Bg + k0 + 64);
            b1 = *(const uint4*)(Bg + k0 + 72);
        }
#pragma unroll
        for (int kc = 0; kc < 2; ++kc) {
            short8 af = *(const short8*)&Al[(wave * 16 + l16) * 72 + kc * 32 + quad * 8];
#pragma unroll
            for (int nt = 0; nt < 4; ++nt) {
                short8 bf = *(const short8*)&Bl[(nt * 16 + l16) * 72 + kc * 32 + quad * 8];
                acc[nt] = __builtin_amdgcn_mfma_f32_16x16x32_bf16(af, bf, acc[nt], 0, 0, 0);
            }
        }
    }
    const int mb = m0 + wave * 16 + quad * 4;
#pragma unroll
    for (int nt = 0; nt < 4; ++nt) {
        const int nn = n0 + nt * 16 + l16;
#pragma unroll
        for (int r = 0; r < 4; ++r) {
            size_t o = (size_t)(mb + r) * N + nn;
            atomicAdd(&out[o], acc[nt][r]);
        }
    }
}

// ---------------- legacy GEMM (fallback) ---------------------------------------
__global__ __launch_bounds__(256) void gemm_k(const ushort_t* __restrict__ A,
        const void* __restrict__ B, long boff, int M, int N, int K, int bt,
        float* __restrict__ outF, ushort_t* __restrict__ outB, void* __restrict__ outD,
        const float* __restrict__ res, int act, const int* __restrict__ flag)
{
    __shared__ ushort_t Al[64 * 40];
    __shared__ ushort_t Bl[64 * 40];
    const int isbf = *flag;
    const int tid = threadIdx.x;
    const int wave = tid >> 6, lane = tid & 63;
    const int quad = lane >> 4, l16 = lane & 15;
    const int m0 = blockIdx.y * 64, n0 = blockIdx.x * 64;
    const int sr = tid >> 2, sc = (tid & 3) * 8;
    const int kr = tid >> 3, nc = (tid & 7) * 8;
    f32x4 acc[4] = {};
    const bool bok = (n0 + sr) < N;
    const ushort_t* Ag = A + (size_t)(m0 + sr) * K + sc;
    const ushort_t* Bb = (const ushort_t*)B + boff;
    const float*    Bf = (const float*)B + boff;
    const size_t i1 = (size_t)(n0 + sr) * K + sc;
    const size_t i0 = (size_t)kr * N + n0 + nc;
    for (int k0 = 0; k0 < K; k0 += 32) {
        uint4 av = *(const uint4*)(Ag + k0);
        ushort_t b8[8] = {0, 0, 0, 0, 0, 0, 0, 0};
        size_t bi = bt ? (i1 + k0) : (i0 + (size_t)k0 * N);
        if (!bt || bok) {
            if (isbf) *(uint4*)b8 = *(const uint4*)(Bb + bi);
            else {
                float4 f0 = *(const float4*)(Bf + bi);
                float4 f1 = *(const float4*)(Bf + bi + 4);
                b8[0] = f2bf(f0.x); b8[1] = f2bf(f0.y); b8[2] = f2bf(f0.z); b8[3] = f2bf(f0.w);
                b8[4] = f2bf(f1.x); b8[5] = f2bf(f1.y); b8[6] = f2bf(f1.z); b8[7] = f2bf(f1.w);
            }
        }
        __syncthreads();
        *(uint4*)&Al[sr * 40 + sc] = av;
        if (bt) *(uint4*)&Bl[sr * 40 + sc] = *(uint4*)b8;
        else {
#pragma unroll
            for (int i = 0; i < 8; ++i) Bl[(nc + i) * 40 + kr] = b8[i];
        }
        __syncthreads();
        short8 af = *(const short8*)&Al[(wave * 16 + l16) * 40 + quad * 8];
#pragma unroll
        for (int nt = 0; nt < 4; ++nt) {
            short8 bf = *(const short8*)&Bl[(nt * 16 + l16) * 40 + quad * 8];
            acc[nt] = __builtin_amdgcn_mfma_f32_16x16x32_bf16(af, bf, acc[nt], 0, 0, 0);
        }
    }
    const int mb = m0 + wave * 16 + quad * 4;
#pragma unroll
    for (int nt = 0; nt < 4; ++nt) {
        int nn = n0 + nt * 16 + l16;
        if (nn >= N) continue;
#pragma unroll
        for (int r = 0; r < 4; ++r) {
            size_t o = (size_t)(mb + r) * N + nn;
            float v = acc[nt][r];
            if (res) v += res[o];
            if (act) v = 0.5f * v * (1.0f + erff(v * 0.70710678118f));
            if (outF)      outF[o] = v;
            else if (outB) outB[o] = f2bf(v);
            else if (isbf) ((ushort_t*)outD)[o] = f2bf(v);
            else           ((float*)outD)[o] = v;
        }
    }
}

// ---------------- flash attention v6: in-reg P + setprio + T1 swizzle ----------
__global__ __launch_bounds__(256) void attn_k(const ushort_t* __restrict__ qkv,
        ushort_t* __restrict__ y)
{
    __shared__ ushort_t Kl[64 * 72];
    __shared__ ushort_t Vt[64 * 72];
    const int tid = threadIdx.x, wave = tid >> 6, lane = tid & 63;
    const int quad = lane >> 4, l16 = lane & 15;
    int xl, yl; xcd_swz(xl, yl);        // all q-tiles of one (b,h) on one XCD
    const int qt = (int)gridDim.x - 1 - xl;   // ascending slots -> long qt first
    const int b = yl >> 3, h = yl & 7;
    const int q0b = qt * 64;
    const int q0w = q0b + wave * 16;
    const size_t rstr = 3 * EMB;
    const ushort_t* qbase = qkv + ((size_t)(b * TS) + q0w + l16) * rstr + h * 64;
    short8 qf0, qf1;
    {   // load Q and pre-scale by 1/8 (exact in bf16)
        ushort_t q0[8], q1[8];
        *(uint4*)q0 = *(const uint4*)(qbase + quad * 8);
        *(uint4*)q1 = *(const uint4*)(qbase + 32 + quad * 8);
#pragma unroll
        for (int i = 0; i < 8; ++i) {
            qf0[i] = (short)f2bf(bf2f(q0[i]) * 0.125f);
            qf1[i] = (short)f2bf(bf2f(q1[i]) * 0.125f);
        }
    }
    f32x4 O[4] = {};
    float lsum = 0.f;
    const int sk = tid >> 2, sdc = (tid & 3) * 16;
    const int vp = tid >> 3, vdc = (tid & 7) * 8;
    const int vsh = 16 * ((tid & 7) & 3);
    // sigma(2*vp): kc=vp>>4, qhat=(vp>>1)&3, ntlow=(vp>>3)&1, r=2*(vp&1)
    const int p0 = ((vp >> 4) << 5) | (((vp >> 1) & 3) << 3)
                 | (((vp >> 3) & 1) << 2) | ((vp & 1) << 1);
    const int vcol = (p0 + vsh) & 63;
    const ushort_t* kbase = qkv + ((size_t)(b * TS) + sk) * rstr + EMB + h * 64 + sdc;
    const ushort_t* vbase = qkv + ((size_t)(b * TS) + 2 * vp) * rstr + 2 * EMB + h * 64 + vdc;
    uint4 kv0 = *(const uint4*)(kbase);
    uint4 kv1 = *(const uint4*)(kbase + 8);
    uint4 vv0 = *(const uint4*)(vbase);
    uint4 vv1 = *(const uint4*)(vbase + rstr);
    for (int kt = 0; kt <= qt; ++kt) {
        __syncthreads();                 // all waves done reading Kl/Vt (prev)
        *(uint4*)&Kl[sk * 72 + sdc]     = kv0;
        *(uint4*)&Kl[sk * 72 + sdc + 8] = kv1;
        {
            ushort_t v0[8], v1[8];
            *(uint4*)v0 = vv0; *(uint4*)v1 = vv1;
#pragma unroll
            for (int i = 0; i < 8; ++i) {
                unsigned pk = (unsigned)v0[i] | ((unsigned)v1[i] << 16);
                *(unsigned*)&Vt[(vdc + i) * 72 + vcol] = pk;
            }
        }
        __syncthreads();                 // tile kt visible
        if (kt < qt) {                   // prefetch kt+1: flies during compute
            const size_t off = (size_t)(kt + 1) * 64 * rstr;
            kv0 = *(const uint4*)(kbase + off);
            kv1 = *(const uint4*)(kbase + off + 8);
            vv0 = *(const uint4*)(vbase + off);
            vv1 = *(const uint4*)(vbase + off + rstr);
        }
        const bool diag = (kt == qt);
        f32x4 S[4] = {};
        __builtin_amdgcn_s_setprio(1);
#pragma unroll
        for (int nt = 0; nt < 4; ++nt) {
            if (diag && nt > wave) continue;
            short8 kf0 = *(const short8*)&Kl[(nt * 16 + l16) * 72 + quad * 8];
            short8 kf1 = *(const short8*)&Kl[(nt * 16 + l16) * 72 + 32 + quad * 8];
            S[nt] = __builtin_amdgcn_mfma_f32_16x16x32_bf16(kf0, qf0, S[nt], 0, 0, 0);
            S[nt] = __builtin_amdgcn_mfma_f32_16x16x32_bf16(kf1, qf1, S[nt], 0, 0, 0);
        }
        __builtin_amdgcn_s_setprio(0);
        unsigned pk[4][2];
#pragma unroll
        for (int nt = 0; nt < 4; ++nt) {
            float p[4];
#pragma unroll
            for (int r = 0; r < 4; ++r) {
                bool live = !diag || (nt * 16 + quad * 4 + r <= wave * 16 + l16);
                p[r] = live ? __expf(S[nt][r]) : 0.f;
                lsum += p[r];
            }
            pk[nt][0] = (unsigned)f2bf(p[0]) | ((unsigned)f2bf(p[1]) << 16);
            pk[nt][1] = (unsigned)f2bf(p[2]) | ((unsigned)f2bf(p[3]) << 16);
        }
        __builtin_amdgcn_s_setprio(1);
#pragma unroll
        for (int kc = 0; kc < 2; ++kc) {
            unsigned pw[4] = {pk[2 * kc][0], pk[2 * kc][1],
                              pk[2 * kc + 1][0], pk[2 * kc + 1][1]};
            short8 pf = *(const short8*)pw;
#pragma unroll
            for (int dt = 0; dt < 4; ++dt) {
                int d = dt * 16 + l16;
                int sh = ((2 * dt + (l16 >> 3)) & 3) * 16;
                int col = (kc * 32 + quad * 8 + sh) & 63;
                short8 vf = *(const short8*)&Vt[d * 72 + col];
                O[dt] = __builtin_amdgcn_mfma_f32_16x16x32_bf16(vf, pf, O[dt], 0, 0, 0);
            }
        }
        __builtin_amdgcn_s_setprio(0);
    }
    lsum += __shfl_xor(lsum, 16, 64);
    lsum += __shfl_xor(lsum, 32, 64);
    const float inv = 1.0f / lsum;
    ushort_t* yb = y + ((size_t)(b * TS) + q0w + l16) * EMB + h * 64 + quad * 4;
#pragma unroll
    for (int dt = 0; dt < 4; ++dt) {
        unsigned ow[2];
        ow[0] = (unsigned)f2bf(O[dt][0] * inv) | ((unsigned)f2bf(O[dt][1] * inv) << 16);
        ow[1] = (unsigned)f2bf(O[dt][2] * inv) | ((unsigned)f2bf(O[dt][3] * inv) << 16);
        *(uint2*)(yb + dt * 16) = *(uint2*)ow;
    }
}

// ---------------- host ---------------------------------------------------------
extern "C" void kernel_launch(void* const* d_in, const int* in_sizes, int n_in,
                              void* d_out, int out_size, void* d_ws, size_t ws_size,
                              hipStream_t stream)
{
    const int*  idx    = (const int*)d_in[0];
    const void* wte    = d_in[1];
    const void* wpe    = d_in[2];
    const void* attn_w = d_in[3];   // [L,512,1536]
    const void* proj_w = d_in[4];   // [L,512,512]
    const void* fc_w   = d_in[5];   // [L,512,2048]
    const void* fcp_w  = d_in[6];   // [L,2048,512]
    const void* ln1_w  = d_in[7];
    const void* ln2_w  = d_in[8];
    const void* lnf_w  = d_in[9];

    const size_t sz_xw    = (size_t)NTOK * EMB * 4;
    const size_t sz_hbf   = (size_t)NTOK * EMB * 2;
    const size_t sz_big   = (size_t)NTOK * 2048 * 2;
    const size_t sz_wteb  = (size_t)VPAD * EMB * 2;
    const size_t sz_wbuf1 = (size_t)3145728 * 2;
    const size_t need_legacy = 256 + sz_xw + sz_hbf + sz_big;
    const size_t need_fast   = need_legacy + sz_wteb + sz_wbuf1;
    const size_t need_all    = need_legacy + sz_wteb + NL * sz_wbuf1;   // ~80 MB

    if (ws_size < need_legacy) {
        sentinel_k<<<(out_size + 255) / 256, 256, 0, stream>>>((ushort_t*)d_out, out_size);
        return;
    }
    int* flag = (int*)d_ws;
    char* p = (char*)d_ws + 256;
    float*    xw  = (float*)p;    p += sz_xw;
    ushort_t* hbf = (ushort_t*)p; p += sz_hbf;
    ushort_t* big = (ushort_t*)p; p += sz_big;

    detect_k<<<1, 64, 0, stream>>>((const ushort_t*)wte, flag);
    embed_k<<<NTOK, 256, 0, stream>>>(idx, wte, wpe, xw, flag);

    if (ws_size >= need_fast) {
        ushort_t* wteb = (ushort_t*)p; p += sz_wteb;
        ushort_t* wbuf = (ushort_t*)p;
        const bool allw = (ws_size >= need_all);
        wconv_k<<<(VPAD * EMB + 255) / 256, 256, 0, stream>>>(wte, wteb,
                VPAD * EMB, VOCAB * EMB, flag);
        if (allw)
            wtrans_k<<<dim3(384, 1, NL), 256, 0, stream>>>(attn_w, proj_w, fc_w, fcp_w,
                    -1, wbuf, flag);
        for (int l = 0; l < NL; ++l) {
            ushort_t* wb = allw ? (wbuf + (size_t)l * 3145728) : wbuf;
            if (!allw)
                wtrans_k<<<dim3(384, 1, 1), 256, 0, stream>>>(attn_w, proj_w, fc_w, fcp_w,
                        (long)l, wbuf, flag);
            ln_k<<<NTOK / 4, 256, 0, stream>>>(xw, ln1_w, (long)l * EMB, hbf, flag);
            gemm_wide<<<dim3(24, 32), 256, 0, stream>>>(hbf, wb,
                    NTOK, 1536, 512, nullptr, big, nullptr, 0);
            attn_k<<<dim3(16, 32), 256, 0, stream>>>(big, hbf);
            gemm_nt<<<dim3(8, 64), 256, 0, stream>>>(hbf, wb + 786432,
                    NTOK, 512, 512, xw, nullptr, nullptr, xw, 0, flag);
            ln_k<<<NTOK / 4, 256, 0, stream>>>(xw, ln2_w, (long)l * EMB, hbf, flag);
            gemm_wide<<<dim3(32, 32), 256, 0, stream>>>(hbf, wb + 1048576,
                    NTOK, 2048, 512, nullptr, big, nullptr, 1 /*gelu*/);
            gemm_sk<<<dim3(8, 64, 2), 256, 0, stream>>>(big, wb + 2097152,
                    NTOK, 512, 2048, xw);
        }
        ln_k<<<NTOK / 4, 256, 0, stream>>>(xw, lnf_w, 0, hbf, flag);
        gemm_nt<<<dim3(6, 64), 256, 0, stream>>>(hbf, wteb,
                NTOK, VOCAB, 512, nullptr, nullptr, d_out, nullptr, 0, flag);
    } else {
        for (int l = 0; l < NL; ++l) {
            ln_k<<<NTOK / 4, 256, 0, stream>>>(xw, ln1_w, (long)l * EMB, hbf, flag);
            gemm_k<<<dim3(24, 64), 256, 0, stream>>>(hbf, attn_w, (long)l * 512 * 1536,
                    NTOK, 1536, 512, 0, nullptr, big, nullptr, nullptr, 0, flag);
            attn_k<<<dim3(16, 32), 256, 0, stream>>>(big, hbf);
            gemm_k<<<dim3(8, 64), 256, 0, stream>>>(hbf, proj_w, (long)l * 512 * 512,
                    NTOK, 512, 512, 0, xw, nullptr, nullptr, xw, 0, flag);
            ln_k<<<NTOK / 4, 256, 0, stream>>>(xw, ln2_w, (long)l * EMB, hbf, flag);
            gemm_k<<<dim3(32, 64), 256, 0, stream>>>(hbf, fc_w, (long)l * 512 * 2048,
                    NTOK, 2048, 512, 0, nullptr, big, nullptr, nullptr, 1, flag);
            gemm_k<<<dim3(8, 64), 256, 0, stream>>>(big, fcp_w, (long)l * 2048 * 512,
                    NTOK, 512, 2048, 0, xw, nullptr, nullptr, xw, 0, flag);
        }
        ln_k<<<NTOK / 4, 256, 0, stream>>>(xw, lnf_w, 0, hbf, flag);
        gemm_k<<<dim3(6, 64), 256, 0, stream>>>(hbf, wte, 0,
                NTOK, VOCAB, 512, 1, nullptr, nullptr, d_out, nullptr, 0, flag);
    }
}